// Round 8
// baseline (262.782 us; speedup 1.0000x reference)
//
#include <hip/hip_runtime.h>
#include <stdint.h>

typedef unsigned short u16;
typedef float f32x4 __attribute__((ext_vector_type(4)));
typedef short s16x8 __attribute__((ext_vector_type(8)));

#define SEQ 2048
#define DM 1024
#define NH 16
#define HD 64
#define BATCH 4
#define ROWS (BATCH*SEQ)   // 8192

__device__ __forceinline__ u16 f32_bf16(float f) {
  union { float f; uint32_t u; } c; c.f = f;
  uint32_t u = c.u;
  return (u16)((u + 0x7fffu + ((u >> 16) & 1u)) >> 16);  // RNE
}
// truncating cast (for P >= 0: bias cancels in softmax normalization)
__device__ __forceinline__ u16 f32_bf16_trunc(float f) {
  union { float f; uint32_t u; } c; c.f = f;
  return (u16)(c.u >> 16);
}

// async global->LDS, 16B per lane. LDS dest = wave-uniform base + lane*16 (NO padding).
#define GLOAD_LDS16(g, l) __builtin_amdgcn_global_load_lds( \
    (__attribute__((address_space(1))) void*)(g),           \
    (__attribute__((address_space(3))) void*)(l), 16, 0, 0)

// ---------------- cast kernels ----------------
__global__ __launch_bounds__(256) void cast_bf16_k(const float* __restrict__ in,
                                                   u16* __restrict__ out, int n4) {
  int i = blockIdx.x * 256 + threadIdx.x;
  if (i >= n4) return;
  float4 v = ((const float4*)in)[i];
  ushort4 o;
  o.x = f32_bf16(v.x); o.y = f32_bf16(v.y); o.z = f32_bf16(v.z); o.w = f32_bf16(v.w);
  ((ushort4*)out)[i] = o;
}

// in [R][C] fp32  ->  out [C][R] bf16
__global__ __launch_bounds__(256) void cast_transpose_k(const float* __restrict__ in,
                                                        u16* __restrict__ out, int R, int C) {
  __shared__ float tile[32][33];
  int c0 = blockIdx.x * 32, r0 = blockIdx.y * 32;
  int t = threadIdx.x;
  int lr = t >> 3, lc = (t & 7) * 4;
  float4 v = *(const float4*)(in + (size_t)(r0 + lr) * C + c0 + lc);
  tile[lr][lc] = v.x; tile[lr][lc + 1] = v.y; tile[lr][lc + 2] = v.z; tile[lr][lc + 3] = v.w;
  __syncthreads();
  ushort4 o;
  o.x = f32_bf16(tile[lc + 0][lr]);
  o.y = f32_bf16(tile[lc + 1][lr]);
  o.z = f32_bf16(tile[lc + 2][lr]);
  o.w = f32_bf16(tile[lc + 3][lr]);
  *(ushort4*)(out + (size_t)(c0 + lr) * R + r0 + lc) = o;
}

#define QSCALE 0.18033688011112042f   // (1/sqrt(64)) * log2(e)

// ---------------- QKV GEMM: 256x256 tile, BK=64 (2x kk-sub-tiles of 32), dbuf-2 ------
// m201-style 4-phase fine interleave (R8). Per K-tile of 64, 4 phases:
//   {ds_read frags (8 or 4 b128); stage one 16KB sub-tile (2 gload_lds); BAR;
//    lgkmcnt(0); sched_barrier; setprio(1) 16 MFMA setprio(0); [vmcnt(4)] BAR}
// ds_reads issued BEFORE the barrier so their latency flies through it; counted
// vmcnt(4) only at phases 2 and 4 (never 0 mid-loop). LDS = 2 dbuf x 2 kk-sub x
// (A 16KB + B 16KB) = 128 KiB; each 32-wide sub-tile keeps the R4 layout + XOR
// involution swizzle (measured 0 bank conflicts).
// vmcnt ledger (per-wave FIFO; cross-wave RAW via vmcnt-BEFORE-barrier):
//   stage order per tile t (for t+1): ph1 A-k0, ph2 B-k0, ph3 A-k1, ph4 B-k1.
//   ph2-end vmcnt(4): outstanding [Ak1,Bk1(t), Ak0,Bk0(t+1)]=8 -> waits Ak1,Bk1(t)
//   (read in ph3/ph4). ph4-end vmcnt(4): outstanding [Ak1,Bk1(t+1), Ak0,Bk0(t+1)
//   ... oldest 4 = Ak0,Bk0(t+1)] -> waits them (read in next tile ph1/ph2).
//   Last tile: no stage; ph2-end vmcnt(0); ph4-end none.
// WAR (stage dbuf = other buf): its last readers completed via lgkm(0) before the
// previous tile's ph4 MFMA, >=2 barriers before the stage issue.
// Accumulation order per acc element: strictly increasing k -> bit-identical to R4.

__device__ __forceinline__ f32x4 mfma16(s16x8 a, s16x8 b, f32x4 c) {
  return __builtin_amdgcn_mfma_f32_16x16x32_bf16(a, b, c, 0, 0, 0);
}

template<int STG, int VM2, int VM4>
__device__ __forceinline__ void qkv_tile(
    const u16* Ac, const u16* Bc,   // current dbuf base (kk0 at +0, kk1 at +8192)
    u16* Asd, u16* Bsd,             // stage dbuf base
    const u16* gA0, const u16* gA1, const u16* gB0, const u16* gB1, // col (T+1)*64
    int d0, int d1, int aoff, int boff,
    f32x4 (&acc)[8][4])
{
  s16x8 bfr[4], af[4];
  // ---- phase 1 (kk0, g0): ds B(k0)+A(g0,k0); stage A-k0(t+1) ----
#pragma unroll
  for (int ni = 0; ni < 4; ++ni) bfr[ni] = *(const s16x8*)&Bc[boff + ni * 512];
#pragma unroll
  for (int mi = 0; mi < 4; ++mi) af[mi] = *(const s16x8*)&Ac[aoff + mi * 512];
  if (STG) { GLOAD_LDS16(gA0, Asd + d0); GLOAD_LDS16(gA1, Asd + d1); }
  __builtin_amdgcn_s_barrier();
  asm volatile("s_waitcnt lgkmcnt(0)" ::: "memory");
  __builtin_amdgcn_sched_barrier(0);
  __builtin_amdgcn_s_setprio(1);
#pragma unroll
  for (int mi = 0; mi < 4; ++mi)
#pragma unroll
    for (int ni = 0; ni < 4; ++ni)
      acc[mi][ni] = mfma16(af[mi], bfr[ni], acc[mi][ni]);
  __builtin_amdgcn_s_setprio(0);
  __builtin_amdgcn_sched_barrier(0);
  __builtin_amdgcn_s_barrier();
  // ---- phase 2 (kk0, g1): ds A(g1,k0); stage B-k0(t+1); vmcnt(VM2) ----
#pragma unroll
  for (int mi = 0; mi < 4; ++mi) af[mi] = *(const s16x8*)&Ac[aoff + 2048 + mi * 512];
  if (STG) { GLOAD_LDS16(gB0, Bsd + d0); GLOAD_LDS16(gB1, Bsd + d1); }
  __builtin_amdgcn_s_barrier();
  asm volatile("s_waitcnt lgkmcnt(0)" ::: "memory");
  __builtin_amdgcn_sched_barrier(0);
  __builtin_amdgcn_s_setprio(1);
#pragma unroll
  for (int mi = 0; mi < 4; ++mi)
#pragma unroll
    for (int ni = 0; ni < 4; ++ni)
      acc[4 + mi][ni] = mfma16(af[mi], bfr[ni], acc[4 + mi][ni]);
  __builtin_amdgcn_s_setprio(0);
  __builtin_amdgcn_sched_barrier(0);
  if (VM2 == 4)      asm volatile("s_waitcnt vmcnt(4)" ::: "memory");
  else if (VM2 == 0) asm volatile("s_waitcnt vmcnt(0)" ::: "memory");
  __builtin_amdgcn_s_barrier();
  // ---- phase 3 (kk1, g0): ds B(k1)+A(g0,k1); stage A-k1(t+1) ----
#pragma unroll
  for (int ni = 0; ni < 4; ++ni) bfr[ni] = *(const s16x8*)&Bc[8192 + boff + ni * 512];
#pragma unroll
  for (int mi = 0; mi < 4; ++mi) af[mi] = *(const s16x8*)&Ac[8192 + aoff + mi * 512];
  if (STG) { GLOAD_LDS16(gA0 + 32, Asd + 8192 + d0); GLOAD_LDS16(gA1 + 32, Asd + 8192 + d1); }
  __builtin_amdgcn_s_barrier();
  asm volatile("s_waitcnt lgkmcnt(0)" ::: "memory");
  __builtin_amdgcn_sched_barrier(0);
  __builtin_amdgcn_s_setprio(1);
#pragma unroll
  for (int mi = 0; mi < 4; ++mi)
#pragma unroll
    for (int ni = 0; ni < 4; ++ni)
      acc[mi][ni] = mfma16(af[mi], bfr[ni], acc[mi][ni]);
  __builtin_amdgcn_s_setprio(0);
  __builtin_amdgcn_sched_barrier(0);
  __builtin_amdgcn_s_barrier();
  // ---- phase 4 (kk1, g1): ds A(g1,k1); stage B-k1(t+1); vmcnt(VM4) ----
#pragma unroll
  for (int mi = 0; mi < 4; ++mi) af[mi] = *(const s16x8*)&Ac[8192 + aoff + 2048 + mi * 512];
  if (STG) { GLOAD_LDS16(gB0 + 32, Bsd + 8192 + d0); GLOAD_LDS16(gB1 + 32, Bsd + 8192 + d1); }
  __builtin_amdgcn_s_barrier();
  asm volatile("s_waitcnt lgkmcnt(0)" ::: "memory");
  __builtin_amdgcn_sched_barrier(0);
  __builtin_amdgcn_s_setprio(1);
#pragma unroll
  for (int mi = 0; mi < 4; ++mi)
#pragma unroll
    for (int ni = 0; ni < 4; ++ni)
      acc[4 + mi][ni] = mfma16(af[mi], bfr[ni], acc[4 + mi][ni]);
  __builtin_amdgcn_s_setprio(0);
  __builtin_amdgcn_sched_barrier(0);
  if (VM4 == 4) asm volatile("s_waitcnt vmcnt(4)" ::: "memory");
  __builtin_amdgcn_s_barrier();
}

__global__ __launch_bounds__(512, 2) void qkv_gemm(
    const u16* __restrict__ A, const u16* __restrict__ Bt,
    u16* __restrict__ Qo, u16* __restrict__ Ko, u16* __restrict__ Vo)
{
  __shared__ u16 lA[2][16384];   // [dbuf][kk-sub(8192) x2] : 256 rows x 32 k bf16 each
  __shared__ u16 lB[2][16384];
  int t = threadIdx.x;

  // XCD-aware bijective remap: 8 XCDs as 4(m) x 2(n); each XCD owns an 8x6 block patch
  int flat = blockIdx.y * 12 + blockIdx.x;   // grid (12, 32), 384 blocks
  int xcd = flat & 7, idx = flat >> 3;       // idx 0..47
  int by = (xcd >> 1) * 8 + idx / 6;
  int bx = (xcd & 1) * 6 + idx % 6;
  int m0 = by * 256, n0 = bx * 256;

  int lane = t & 63, w = t >> 6;
  int m16 = lane & 15, quad = lane >> 4;
  int wm = w >> 2, wn = w & 3;               // 2 x 4 wave grid

  // staging per 32-wide sub-tile: 1024 16B-chunks; thread t covers chunks t, 512+t.
  // chunk c: row = c>>2, slot j = c&3; source slot = j ^ ((c>>3)&3) (involution).
  int r0 = t >> 2;
  int scol = ((t & 3) ^ ((t >> 3) & 3)) * 8; // pre-swizzled source column (elements)
  const u16* Ag0 = A  + (size_t)(m0 + r0) * DM + scol;
  const u16* Ag1 = A  + (size_t)(m0 + 128 + r0) * DM + scol;
  const u16* Bg0 = Bt + (size_t)(n0 + r0) * DM + scol;
  const u16* Bg1 = Bt + (size_t)(n0 + 128 + r0) * DM + scol;
  int d0 = t * 8, d1 = 4096 + t * 8;         // linear LDS dests within a sub-tile

  // fragment reads: row*32 + (quad ^ ((row>>1)&3))*8 ; (row>>1)&3 == (m16>>1)&3
  int ka = (quad ^ ((m16 >> 1) & 3)) * 8;
  int aoff = (wm * 128 + m16) * 32 + ka;
  int boff = (wn * 64 + m16) * 32 + ka;

  f32x4 acc[8][4];
#pragma unroll
  for (int mi = 0; mi < 8; ++mi)
#pragma unroll
    for (int ni = 0; ni < 4; ++ni)
#pragma unroll
      for (int r = 0; r < 4; ++r) acc[mi][ni][r] = 0.f;

  // prologue: stage K-tile 0 (8 loads in ledger order Ak0,Bk0,Ak1,Bk1);
  // vmcnt(4) -> k0 sub-tiles landed; barrier publishes cross-wave.
  GLOAD_LDS16(Ag0, lA[0] + d0);
  GLOAD_LDS16(Ag1, lA[0] + d1);
  GLOAD_LDS16(Bg0, lB[0] + d0);
  GLOAD_LDS16(Bg1, lB[0] + d1);
  GLOAD_LDS16(Ag0 + 32, lA[0] + 8192 + d0);
  GLOAD_LDS16(Ag1 + 32, lA[0] + 8192 + d1);
  GLOAD_LDS16(Bg0 + 32, lB[0] + 8192 + d0);
  GLOAD_LDS16(Bg1 + 32, lB[0] + 8192 + d1);
  asm volatile("s_waitcnt vmcnt(4)" ::: "memory");
  __builtin_amdgcn_s_barrier();
  __builtin_amdgcn_sched_barrier(0);

  // main loop: K-tiles 0..14 (stage T+1), tail tile 15 (no stage, drain)
  for (int T = 0; T < 15; ++T) {
    int db = T & 1;
    qkv_tile<1, 4, 4>(lA[db], lB[db], lA[db ^ 1], lB[db ^ 1],
                      Ag0 + (T + 1) * 64, Ag1 + (T + 1) * 64,
                      Bg0 + (T + 1) * 64, Bg1 + (T + 1) * 64,
                      d0, d1, aoff, boff, acc);
  }
  qkv_tile<0, 0, -1>(lA[1], lB[1], lA[0], lB[0],
                     Ag0, Ag1, Bg0, Bg1, d0, d1, aoff, boff, acc);

  // epilogue: split Q (scaled) / K / V (transposed) — per-wave 64-col span stays
  // within one section and one head (n0, wn*64 are 64-aligned)
#pragma unroll
  for (int mi = 0; mi < 8; ++mi) {
    int gr = m0 + wm * 128 + mi * 16 + quad * 4;   // multiple of 4, no batch crossing
    int b = gr >> 11, tt = gr & 2047;
#pragma unroll
    for (int ni = 0; ni < 4; ++ni) {
      int gc = n0 + wn * 64 + ni * 16 + m16;
      int sec = gc >> 10, rem = gc & 1023, h = rem >> 6, d = rem & 63;
      if (sec == 0) {
#pragma unroll
        for (int r = 0; r < 4; ++r)
          Qo[(((size_t)b * NH + h) * SEQ + tt + r) * HD + d] = f32_bf16(acc[mi][ni][r] * QSCALE);
      } else if (sec == 1) {
#pragma unroll
        for (int r = 0; r < 4; ++r)
          Ko[(((size_t)b * NH + h) * SEQ + tt + r) * HD + d] = f32_bf16(acc[mi][ni][r]);
      } else {
        ushort4 o;
        o.x = f32_bf16(acc[mi][ni][0]); o.y = f32_bf16(acc[mi][ni][1]);
        o.z = f32_bf16(acc[mi][ni][2]); o.w = f32_bf16(acc[mi][ni][3]);
        *(ushort4*)&Vo[(((size_t)b * NH + h) * HD + d) * SEQ + tt] = o;  // V^T [b][h][d][t]
      }
    }
  }
}

// ---------------- GEMM (out-proj): C[M,N] = A[M,K] * Bt[N,K]^T, bf16 in, fp32 out ----
template<int EPI>
__global__ __launch_bounds__(256) void gemm_bt(
    const u16* __restrict__ A, const u16* __restrict__ Bt,
    float* __restrict__ Cf, u16* __restrict__ Qo, u16* __restrict__ Ko, u16* __restrict__ Vo,
    int M, int N, int K)
{
  __shared__ u16 As[128 * 32];
  __shared__ u16 Bs[128 * 32];
  int t = threadIdx.x;
  int m0 = blockIdx.y * 128, n0 = blockIdx.x * 128;

  int srow = t >> 2, scol8 = (t & 3) * 8;
  const u16* Ag0 = A  + (size_t)(m0 + srow) * K + scol8;
  const u16* Ag1 = A  + (size_t)(m0 + 64 + srow) * K + scol8;
  const u16* Bg0 = Bt + (size_t)(n0 + srow) * K + scol8;
  const u16* Bg1 = Bt + (size_t)(n0 + 64 + srow) * K + scol8;
  u16* Al0 = As + t * 8;  u16* Al1 = As + 2048 + t * 8;
  u16* Bl0 = Bs + t * 8;  u16* Bl1 = Bs + 2048 + t * 8;

  int lane = t & 63, w = t >> 6;
  int m16 = lane & 15, quad = lane >> 4;
  int wr = (w >> 1) * 64, wc = (w & 1) * 64;

  f32x4 acc[4][4];
#pragma unroll
  for (int mi = 0; mi < 4; ++mi)
#pragma unroll
    for (int ni = 0; ni < 4; ++ni)
#pragma unroll
      for (int r = 0; r < 4; ++r) acc[mi][ni][r] = 0.f;

  for (int k0 = 0; k0 < K; k0 += 32) {
    __syncthreads();
    GLOAD_LDS16(Ag0 + k0, Al0);
    GLOAD_LDS16(Ag1 + k0, Al1);
    GLOAD_LDS16(Bg0 + k0, Bl0);
    GLOAD_LDS16(Bg1 + k0, Bl1);
    __syncthreads();
    s16x8 af[4], bf[4];
#pragma unroll
    for (int mi = 0; mi < 4; ++mi)
      af[mi] = *(const s16x8*)(As + (wr + mi * 16 + m16) * 32 + quad * 8);
#pragma unroll
    for (int ni = 0; ni < 4; ++ni)
      bf[ni] = *(const s16x8*)(Bs + (wc + ni * 16 + m16) * 32 + quad * 8);
#pragma unroll
    for (int mi = 0; mi < 4; ++mi)
#pragma unroll
      for (int ni = 0; ni < 4; ++ni)
        acc[mi][ni] = __builtin_amdgcn_mfma_f32_16x16x32_bf16(af[mi], bf[ni], acc[mi][ni], 0, 0, 0);
  }

  if (EPI == 0) {
#pragma unroll
    for (int mi = 0; mi < 4; ++mi) {
      int gr = m0 + wr + mi * 16 + quad * 4;
#pragma unroll
      for (int ni = 0; ni < 4; ++ni) {
        int gc = n0 + wc + ni * 16 + m16;
#pragma unroll
        for (int r = 0; r < 4; ++r)
          Cf[(size_t)(gr + r) * N + gc] = acc[mi][ni][r];
      }
    }
  } else {
#pragma unroll
    for (int mi = 0; mi < 4; ++mi) {
      int gr = m0 + wr + mi * 16 + quad * 4;
      int b = gr >> 11, tt = gr & 2047;
#pragma unroll
      for (int ni = 0; ni < 4; ++ni) {
        int gc = n0 + wc + ni * 16 + m16;
        int sec = gc >> 10, rem = gc & 1023, h = rem >> 6, d = rem & 63;
        if (sec == 0) {
#pragma unroll
          for (int r = 0; r < 4; ++r)
            Qo[(((size_t)b * NH + h) * SEQ + tt + r) * HD + d] = f32_bf16(acc[mi][ni][r] * QSCALE);
        } else if (sec == 1) {
#pragma unroll
          for (int r = 0; r < 4; ++r)
            Ko[(((size_t)b * NH + h) * SEQ + tt + r) * HD + d] = f32_bf16(acc[mi][ni][r]);
        } else {
          ushort4 o;
          o.x = f32_bf16(acc[mi][ni][0]); o.y = f32_bf16(acc[mi][ni][1]);
          o.z = f32_bf16(acc[mi][ni][2]); o.w = f32_bf16(acc[mi][ni][3]);
          *(ushort4*)&Vo[(((size_t)b * NH + h) * HD + d) * SEQ + tt] = o;
        }
      }
    }
  }
}

// ---------------- flash attention, causal, QBLK=128, swapped-QK^T, NO-MAX softmax ------
// (R4 version, verbatim — 27 KB LDS, 4-5 blocks/CU TLP hides load latency; R6's
// double-buffer regressed via occupancy. Do not touch.)
__global__ __launch_bounds__(256) void attn_k(
    const u16* __restrict__ Q, const u16* __restrict__ K,
    const u16* __restrict__ Vt_g,   // [B,H,HD,SEQ]
    u16* __restrict__ O)
{
  __shared__ u16 Ks[64][72];      // [key][d]   (144B rows: 16B-aligned)
  __shared__ u16 Vt[64][72];      // [d][key]
  __shared__ u16 Ps[4][32][72];   // per wave: [qrow 0..31][key]
  int flat = blockIdx.y * 8 + blockIdx.x;    // grid (8, 64) = 512 blocks
  int xcd = flat & 7, pos = flat >> 3;
  int bh = xcd * 8 + (pos >> 3);             // 8 bh per XCD
  int xb = pos & 7;                          // 0..7
  int t = threadIdx.x, w = t >> 6, lane = t & 63;
  int m16 = lane & 15, quad = lane >> 4;
  int b = bh >> 4, h = bh & 15;

  int srow = t >> 2, sc = (t & 3) * 16;
  const u16* Kg0 = K    + ((size_t)bh * SEQ + srow) * HD  + sc;   // key=srow, d=sc..
  const u16* Vg0 = Vt_g + ((size_t)bh * HD  + srow) * SEQ + sc;   // d=srow,  key=sc..

  for (int half = 0; half < 2; ++half) {
    int qt = half ? (15 - xb) : xb;
    int q0 = qt * 128;

    // Q frags: set A rows q0 + w*32 + m16, set B rows +16 (scale pre-folded into Q)
    const u16* QbA = Q + ((size_t)bh * SEQ + q0 + w * 32 + m16) * HD + quad * 8;
    s16x8 qA0 = *(const s16x8*)QbA;
    s16x8 qA1 = *(const s16x8*)(QbA + 32);
    s16x8 qB0 = *(const s16x8*)(QbA + 16 * HD);
    s16x8 qB1 = *(const s16x8*)(QbA + 16 * HD + 32);

    f32x4 accA[4], accB[4];
    float lA = 0.f, lB = 0.f;
#pragma unroll
    for (int ni = 0; ni < 4; ++ni)
#pragma unroll
      for (int r = 0; r < 4; ++r) { accA[ni][r] = 0.f; accB[ni][r] = 0.f; }

    int ktmax = 2 * qt + 1;
    for (int kt = 0; kt <= ktmax; ++kt) {
      uint4 kv0 = *(const uint4*)(Kg0 + (size_t)kt * 64 * HD);
      uint4 kv1 = *(const uint4*)(Kg0 + (size_t)kt * 64 * HD + 8);
      uint4 vv0 = *(const uint4*)(Vg0 + kt * 64);
      uint4 vv1 = *(const uint4*)(Vg0 + kt * 64 + 8);
      __syncthreads();   // previous tile's LDS reads done
      *(uint4*)&Ks[srow][sc]     = kv0;
      *(uint4*)&Ks[srow][sc + 8] = kv1;
      *(uint4*)&Vt[srow][sc]     = vv0;
      *(uint4*)&Vt[srow][sc + 8] = vv1;
      __syncthreads();

      // S^T = K Q^T
      f32x4 sA[4], sB[4];
#pragma unroll
      for (int ni = 0; ni < 4; ++ni)
#pragma unroll
        for (int r = 0; r < 4; ++r) { sA[ni][r] = 0.f; sB[ni][r] = 0.f; }
#pragma unroll
      for (int ni = 0; ni < 4; ++ni) {
        s16x8 kf0 = *(const s16x8*)&Ks[ni * 16 + m16][quad * 8];
        s16x8 kf1 = *(const s16x8*)&Ks[ni * 16 + m16][32 + quad * 8];
        sA[ni] = mfma16(kf0, qA0, sA[ni]);
        sA[ni] = mfma16(kf1, qA1, sA[ni]);
        sB[ni] = mfma16(kf0, qB0, sB[ni]);
        sB[ni] = mfma16(kf1, qB1, sB[ni]);
      }
      if (kt >= 2 * qt) {   // diagonal region: causal mask (exp2(-1e30) -> 0)
        int qga = q0 + w * 32 + m16;
#pragma unroll
        for (int ni = 0; ni < 4; ++ni) {
          int kb = kt * 64 + ni * 16 + quad * 4;
#pragma unroll
          for (int r = 0; r < 4; ++r) {
            if (kb + r > qga)      sA[ni][r] = -1e30f;
            if (kb + r > qga + 16) sB[ni][r] = -1e30f;
          }
        }
      }

      // p = exp2(S); per-lane l partial (q = m16 row); P write as ushort4 (b64)
#pragma unroll
      for (int ni = 0; ni < 4; ++ni) {
        ushort4 oA, oB;
#pragma unroll
        for (int r = 0; r < 4; ++r) {
          float pA = __builtin_amdgcn_exp2f(sA[ni][r]);
          float pB = __builtin_amdgcn_exp2f(sB[ni][r]);
          lA += pA; lB += pB;
          ((u16*)&oA)[r] = f32_bf16_trunc(pA);
          ((u16*)&oB)[r] = f32_bf16_trunc(pB);
        }
        *(ushort4*)&Ps[w][m16][ni * 16 + quad * 4]      = oA;
        *(ushort4*)&Ps[w][16 + m16][ni * 16 + quad * 4] = oB;
      }

      // no barrier: Ps is same-wave write->read, ordered by lgkmcnt
#pragma unroll
      for (int ks = 0; ks < 2; ++ks) {
        s16x8 pA = *(const s16x8*)&Ps[w][m16][ks * 32 + quad * 8];
        s16x8 pB = *(const s16x8*)&Ps[w][16 + m16][ks * 32 + quad * 8];
#pragma unroll
        for (int ni = 0; ni < 4; ++ni) {
          s16x8 vf = *(const s16x8*)&Vt[ni * 16 + m16][ks * 32 + quad * 8];
          accA[ni] = mfma16(pA, vf, accA[ni]);
          accB[ni] = mfma16(pB, vf, accB[ni]);
        }
      }
    }

    // l: reduce over the 4 quad lanes (keys split across quads)
    lA += __shfl_xor(lA, 16, 64);
    lA += __shfl_xor(lA, 32, 64);
    lB += __shfl_xor(lB, 16, 64);
    lB += __shfl_xor(lB, 32, 64);

    // epilogue: O rows q = q0 + w*32 + (quad*4+r) [+16 for set B]; l lives at
    // lanes with m16 == qrow -> redistribute with one shfl per r
#pragma unroll
    for (int r = 0; r < 4; ++r) {
      int src = (lane & 48) | (quad * 4 + r);
      float la = __shfl(lA, src, 64);
      float lb = __shfl(lB, src, 64);
      float ia = 1.f / la, ib = 1.f / lb;
      int qa = q0 + w * 32 + quad * 4 + r;
      size_t baseA = ((size_t)(b * SEQ + qa)) * DM + h * HD;
      size_t baseB = baseA + (size_t)16 * DM;
#pragma unroll
      for (int ni = 0; ni < 4; ++ni) {
        O[baseA + ni * 16 + m16] = f32_bf16(accA[ni][r] * ia);
        O[baseB + ni * 16 + m16] = f32_bf16(accB[ni][r] * ib);
      }
    }
  }
}

// ---------------- launch ----------------
extern "C" void kernel_launch(void* const* d_in, const int* in_sizes, int n_in,
                              void* d_out, int out_size, void* d_ws, size_t ws_size,
                              hipStream_t stream) {
  const float* x    = (const float*)d_in[0];   // [4,2048,1024]
  const float* Wqkv = (const float*)d_in[1];   // [1024,3072]
  const float* Wout = (const float*)d_in[2];   // [1024,1024]
  float* out = (float*)d_out;                  // [4,2048,1024] fp32

  u16* ws = (u16*)d_ws;
  size_t off = 0;
  u16* x_bf   = ws + off; off += (size_t)ROWS * DM;
  u16* wqkv_t = ws + off; off += (size_t)(3 * DM) * DM;
  u16* wout_t = ws + off; off += (size_t)DM * DM;
  u16* Qb     = ws + off; off += (size_t)BATCH * NH * SEQ * HD;
  u16* Kb     = ws + off; off += (size_t)BATCH * NH * SEQ * HD;
  u16* Vb     = ws + off; off += (size_t)BATCH * NH * SEQ * HD;  // [B,H,HD,T]
  u16* AO     = ws + off; off += (size_t)ROWS * DM;

  cast_bf16_k<<<(ROWS * DM / 4 + 255) / 256, 256, 0, stream>>>(x, x_bf, ROWS * DM / 4);
  cast_transpose_k<<<dim3(3 * DM / 32, DM / 32), 256, 0, stream>>>(Wqkv, wqkv_t, DM, 3 * DM);
  cast_transpose_k<<<dim3(DM / 32, DM / 32), 256, 0, stream>>>(Wout, wout_t, DM, DM);
  qkv_gemm<<<dim3(12, 32), 512, 0, stream>>>(x_bf, wqkv_t, Qb, Kb, Vb);
  attn_k<<<dim3(8, BATCH * NH), 256, 0, stream>>>(Qb, Kb, Vb, AO);
  gemm_bt<0><<<dim3(DM / 128, ROWS / 128), 256, 0, stream>>>(
      AO, wout_t, out, nullptr, nullptr, nullptr, ROWS, DM, DM);
}

// Round 9
// 257.825 us; speedup vs baseline: 1.0192x; 1.0192x over previous
//
#include <hip/hip_runtime.h>
#include <stdint.h>

typedef unsigned short u16;
typedef float f32x4 __attribute__((ext_vector_type(4)));
typedef short s16x8 __attribute__((ext_vector_type(8)));

#define SEQ 2048
#define DM 1024
#define NH 16
#define HD 64
#define BATCH 4
#define ROWS (BATCH*SEQ)   // 8192

__device__ __forceinline__ u16 f32_bf16(float f) {
  union { float f; uint32_t u; } c; c.f = f;
  uint32_t u = c.u;
  return (u16)((u + 0x7fffu + ((u >> 16) & 1u)) >> 16);  // RNE
}
// truncating cast (for P >= 0: bias cancels in softmax normalization)
__device__ __forceinline__ u16 f32_bf16_trunc(float f) {
  union { float f; uint32_t u; } c; c.f = f;
  return (u16)(c.u >> 16);
}

// async global->LDS, 16B per lane. LDS dest = wave-uniform base + lane*16 (NO padding).
#define GLOAD_LDS16(g, l) __builtin_amdgcn_global_load_lds( \
    (__attribute__((address_space(1))) void*)(g),           \
    (__attribute__((address_space(3))) void*)(l), 16, 0, 0)

// ---------------- cast kernels ----------------
__global__ __launch_bounds__(256) void cast_bf16_k(const float* __restrict__ in,
                                                   u16* __restrict__ out, int n4) {
  int i = blockIdx.x * 256 + threadIdx.x;
  if (i >= n4) return;
  float4 v = ((const float4*)in)[i];
  ushort4 o;
  o.x = f32_bf16(v.x); o.y = f32_bf16(v.y); o.z = f32_bf16(v.z); o.w = f32_bf16(v.w);
  ((ushort4*)out)[i] = o;
}

// in [R][C] fp32  ->  out [C][R] bf16
__global__ __launch_bounds__(256) void cast_transpose_k(const float* __restrict__ in,
                                                        u16* __restrict__ out, int R, int C) {
  __shared__ float tile[32][33];
  int c0 = blockIdx.x * 32, r0 = blockIdx.y * 32;
  int t = threadIdx.x;
  int lr = t >> 3, lc = (t & 7) * 4;
  float4 v = *(const float4*)(in + (size_t)(r0 + lr) * C + c0 + lc);
  tile[lr][lc] = v.x; tile[lr][lc + 1] = v.y; tile[lr][lc + 2] = v.z; tile[lr][lc + 3] = v.w;
  __syncthreads();
  ushort4 o;
  o.x = f32_bf16(tile[lc + 0][lr]);
  o.y = f32_bf16(tile[lc + 1][lr]);
  o.z = f32_bf16(tile[lc + 2][lr]);
  o.w = f32_bf16(tile[lc + 3][lr]);
  *(ushort4*)(out + (size_t)(c0 + lr) * R + r0 + lc) = o;
}

#define QSCALE 0.18033688011112042f   // (1/sqrt(64)) * log2(e)

// ---------------- QKV GEMM: 128x384 tile, BK=32, ring-4 LDS, overlapped pipeline ------
// R9: same verified R4/R7 schedule (2 barriers/tile, cross-tile reg prefetch, counted
// vmcnt(8)=2 tiles in flight, XOR involution swizzle), reshaped to BM=128 x BN=384 so
// grid = (8,64) = 512 blocks = EXACTLY 2 full rounds (the 384-block grid lost 25% to a
// half-empty second round; R5's wider-tile fix spilled at ~320 VGPR — this shape needs
// only acc[4][6]=96 + frags 72 + addr ~ 195 VGPR).
// Per wave (8 = 2M x 4N): output 64x96, 24 MFMA/tile in 2 clusters of 12.
// Staging per tile: A 8KB = 1 gload/thread, B 24KB = 3 gloads/thread (4 total; ledger
// identical to R4's 4-load tiles: prologue 3 tiles = 12 loads, vmcnt(8) -> tile0 in).
// lgkm counts: phase0 lgkm(2) (f1[2] in flight), phase1 lgkm(8) (na[2]+nb[6] in flight).

__device__ __forceinline__ f32x4 mfma16(s16x8 a, s16x8 b, f32x4 c) {
  return __builtin_amdgcn_mfma_f32_16x16x32_bf16(a, b, c, 0, 0, 0);
}

template<int STG, int ENDVM, int LAST>
__device__ __forceinline__ void tile_step(
    const u16* lAc, const u16* lBc,   // buf T (current)
    const u16* lAn, const u16* lBn,   // buf T+1 (next; frag prefetch source)
    u16* lAs, u16* lBs,               // buf T+3 (stage dest)
    const u16* gA, const u16* gB0, const u16* gB1, const u16* gB2,
    int d0, int aoff, int boff,
    s16x8 (&fa)[2], s16x8 (&fb)[6],   // tile T phase-0 frags (preloaded last tile)
    s16x8 (&na)[2], s16x8 (&nb)[6],   // tile T+1 frag storage (ping-pong)
    f32x4 (&acc)[4][6])
{
  __builtin_amdgcn_s_barrier();                       // bar2 (WAR fence for stage)
  __builtin_amdgcn_sched_barrier(0);
  s16x8 f1[2];                                        // A-high frags (rows +32,+48)
#pragma unroll
  for (int mi = 0; mi < 2; ++mi) f1[mi] = *(const s16x8*)&lAc[aoff + 1024 + mi * 512];
  if (STG) { GLOAD_LDS16(gA, lAs + d0); }
  asm volatile("s_waitcnt lgkmcnt(2)" ::: "memory");  // fa/fb resident; f1 in flight
  __builtin_amdgcn_sched_barrier(0);
  __builtin_amdgcn_s_setprio(1);
#pragma unroll
  for (int mi = 0; mi < 2; ++mi)
#pragma unroll
    for (int ni = 0; ni < 6; ++ni)
      acc[mi][ni] = mfma16(fa[mi], fb[ni], acc[mi][ni]);
  __builtin_amdgcn_s_setprio(0);
  __builtin_amdgcn_sched_barrier(0);
  if (STG) {
    GLOAD_LDS16(gB0, lBs + d0);
    GLOAD_LDS16(gB1, lBs + 4096 + d0);
    GLOAD_LDS16(gB2, lBs + 8192 + d0);
  }
  if (ENDVM == 8)      asm volatile("s_waitcnt vmcnt(8)" ::: "memory");
  else if (ENDVM == 4) asm volatile("s_waitcnt vmcnt(4)" ::: "memory");
  else if (ENDVM == 0) asm volatile("s_waitcnt vmcnt(0)" ::: "memory");
  __builtin_amdgcn_s_barrier();                       // bar1: buf T+1 ready for reads
  __builtin_amdgcn_sched_barrier(0);
  if (!LAST) {
#pragma unroll
    for (int ni = 0; ni < 6; ++ni) nb[ni] = *(const s16x8*)&lBn[boff + ni * 512];
#pragma unroll
    for (int mi = 0; mi < 2; ++mi) na[mi] = *(const s16x8*)&lAn[aoff + mi * 512];
    asm volatile("s_waitcnt lgkmcnt(8)" ::: "memory"); // f1 resident; na/nb in flight
  } else {
    asm volatile("s_waitcnt lgkmcnt(0)" ::: "memory");
  }
  __builtin_amdgcn_sched_barrier(0);
  __builtin_amdgcn_s_setprio(1);
#pragma unroll
  for (int mi = 0; mi < 2; ++mi)
#pragma unroll
    for (int ni = 0; ni < 6; ++ni)
      acc[2 + mi][ni] = mfma16(f1[mi], fb[ni], acc[2 + mi][ni]);
  __builtin_amdgcn_s_setprio(0);
  __builtin_amdgcn_sched_barrier(0);
}

__global__ __launch_bounds__(512, 2) void qkv_gemm(
    const u16* __restrict__ A, const u16* __restrict__ Bt,
    u16* __restrict__ Qo, u16* __restrict__ Ko, u16* __restrict__ Vo)
{
  __shared__ u16 lA[4][4096];    // 4 ring bufs x [128 rows][32 k] bf16 (8 KB each)
  __shared__ u16 lB[4][12288];   // 4 ring bufs x [384 rows][32 k] bf16 (24 KB each)
  int t = threadIdx.x;

  // XCD-aware bijective remap: 8 XCDs as 4(m) x 2(n); each XCD owns a 16x4 block patch
  // (A 16x128 rows = 4 MB + B 4x384 cols = 3 MB -> 7 MB working set, same as R7)
  int flat = blockIdx.y * 8 + blockIdx.x;    // grid (8, 64), 512 blocks
  int xcd = flat & 7, idx = flat >> 3;       // idx 0..63
  int by = (xcd >> 1) * 16 + (idx >> 2);     // 0..63
  int bx = (xcd & 1) * 4 + (idx & 3);        // 0..7
  int m0 = by * 128, n0 = bx * 384;

  int lane = t & 63, w = t >> 6;
  int m16 = lane & 15, quad = lane >> 4;
  int wm = w >> 2, wn = w & 3;               // 2 x 4 wave grid

  // staging: 16B chunks; chunk c: row=c>>2, slot j=c&3; source slot = j ^ ((row>>1)&3).
  int r0 = t >> 2;
  int scol = ((t & 3) ^ ((t >> 3) & 3)) * 8; // pre-swizzled source column (elements)
  const u16* Ag  = A  + (size_t)(m0 + r0) * DM + scol;
  const u16* Bg0 = Bt + (size_t)(n0 + r0) * DM + scol;
  const u16* Bg1 = Bt + (size_t)(n0 + 128 + r0) * DM + scol;
  const u16* Bg2 = Bt + (size_t)(n0 + 256 + r0) * DM + scol;
  int d0 = t * 8;                            // linear LDS dest (elements)

  // fragment reads: row*32 + (quad ^ ((row>>1)&3))*8 ; (row>>1)&3 == (m16>>1)&3
  int ka = (quad ^ ((m16 >> 1) & 3)) * 8;
  int aoff = (wm * 64 + m16) * 32 + ka;
  int boff = (wn * 96 + m16) * 32 + ka;

  f32x4 acc[4][6];
#pragma unroll
  for (int mi = 0; mi < 4; ++mi)
#pragma unroll
    for (int ni = 0; ni < 6; ++ni)
#pragma unroll
      for (int r = 0; r < 4; ++r) acc[mi][ni][r] = 0.f;

  // prologue: stage tiles 0..2 (12 loads/thread), wait tile 0 (2 tiles stay in flight)
#pragma unroll
  for (int kt = 0; kt < 3; ++kt) {
    GLOAD_LDS16(Ag + kt * 32, lA[kt] + d0);
    GLOAD_LDS16(Bg0 + kt * 32, lB[kt] + d0);
    GLOAD_LDS16(Bg1 + kt * 32, lB[kt] + 4096 + d0);
    GLOAD_LDS16(Bg2 + kt * 32, lB[kt] + 8192 + d0);
  }
  asm volatile("s_waitcnt vmcnt(8)" ::: "memory");
  __builtin_amdgcn_s_barrier();
  __builtin_amdgcn_sched_barrier(0);

  // initial phase-0 fragments of tile 0 (ping-pong set 0)
  s16x8 fa0[2], fa1[2];
  s16x8 fb0[6], fb1[6];
#pragma unroll
  for (int ni = 0; ni < 6; ++ni) fb0[ni] = *(const s16x8*)&lB[0][boff + ni * 512];
#pragma unroll
  for (int mi = 0; mi < 2; ++mi) fa0[mi] = *(const s16x8*)&lA[0][aoff + mi * 512];

  // main loop: tiles 0..27 (pairs keep the reg ping-pong static)
  for (int it = 0; it < 14; ++it) {
    int T = 2 * it;
    tile_step<1, 8, 0>(lA[T & 3], lB[T & 3], lA[(T + 1) & 3], lB[(T + 1) & 3],
                       lA[(T + 3) & 3], lB[(T + 3) & 3],
                       Ag + (T + 3) * 32,
                       Bg0 + (T + 3) * 32, Bg1 + (T + 3) * 32, Bg2 + (T + 3) * 32,
                       d0, aoff, boff, fa0, fb0, fa1, fb1, acc);
    tile_step<1, 8, 0>(lA[(T + 1) & 3], lB[(T + 1) & 3], lA[(T + 2) & 3], lB[(T + 2) & 3],
                       lA[(T + 4) & 3], lB[(T + 4) & 3],
                       Ag + (T + 4) * 32,
                       Bg0 + (T + 4) * 32, Bg1 + (T + 4) * 32, Bg2 + (T + 4) * 32,
                       d0, aoff, boff, fa1, fb1, fa0, fb0, acc);
  }
  // tile 28 (stages tile 31), then 29,30,31 draining vmcnt 8 -> 4 -> 0
  tile_step<1, 8, 0>(lA[0], lB[0], lA[1], lB[1], lA[3], lB[3],
                     Ag + 31 * 32, Bg0 + 31 * 32, Bg1 + 31 * 32, Bg2 + 31 * 32,
                     d0, aoff, boff, fa0, fb0, fa1, fb1, acc);
  tile_step<0, 4, 0>(lA[1], lB[1], lA[2], lB[2], lA[0], lB[0],
                     Ag, Bg0, Bg1, Bg2, d0, aoff, boff, fa1, fb1, fa0, fb0, acc);
  tile_step<0, 0, 0>(lA[2], lB[2], lA[3], lB[3], lA[0], lB[0],
                     Ag, Bg0, Bg1, Bg2, d0, aoff, boff, fa0, fb0, fa1, fb1, acc);
  tile_step<0, -1, 1>(lA[3], lB[3], lA[0], lB[0], lA[0], lB[0],
                      Ag, Bg0, Bg1, Bg2, d0, aoff, boff, fa1, fb1, fa0, fb0, acc);

  // epilogue: split Q (scaled) / K / V (transposed). sec/h/d per 16-col group;
  // all column offsets are multiples of 16 so groups never straddle 16-aligned bins.
#pragma unroll
  for (int mi = 0; mi < 4; ++mi) {
    int gr = m0 + wm * 64 + mi * 16 + quad * 4;   // multiple of 4, no batch crossing
    int b = gr >> 11, tt = gr & 2047;
#pragma unroll
    for (int ni = 0; ni < 6; ++ni) {
      int gc = n0 + wn * 96 + ni * 16 + m16;
      int sec = gc >> 10, rem = gc & 1023, h = rem >> 6, d = rem & 63;
      if (sec == 0) {
#pragma unroll
        for (int r = 0; r < 4; ++r)
          Qo[(((size_t)b * NH + h) * SEQ + tt + r) * HD + d] = f32_bf16(acc[mi][ni][r] * QSCALE);
      } else if (sec == 1) {
#pragma unroll
        for (int r = 0; r < 4; ++r)
          Ko[(((size_t)b * NH + h) * SEQ + tt + r) * HD + d] = f32_bf16(acc[mi][ni][r]);
      } else {
        ushort4 o;
        o.x = f32_bf16(acc[mi][ni][0]); o.y = f32_bf16(acc[mi][ni][1]);
        o.z = f32_bf16(acc[mi][ni][2]); o.w = f32_bf16(acc[mi][ni][3]);
        *(ushort4*)&Vo[(((size_t)b * NH + h) * HD + d) * SEQ + tt] = o;  // V^T [b][h][d][t]
      }
    }
  }
}

// ---------------- GEMM (out-proj): C[M,N] = A[M,K] * Bt[N,K]^T, bf16 in, fp32 out ----
template<int EPI>
__global__ __launch_bounds__(256) void gemm_bt(
    const u16* __restrict__ A, const u16* __restrict__ Bt,
    float* __restrict__ Cf, u16* __restrict__ Qo, u16* __restrict__ Ko, u16* __restrict__ Vo,
    int M, int N, int K)
{
  __shared__ u16 As[128 * 32];
  __shared__ u16 Bs[128 * 32];
  int t = threadIdx.x;
  int m0 = blockIdx.y * 128, n0 = blockIdx.x * 128;

  int srow = t >> 2, scol8 = (t & 3) * 8;
  const u16* Ag0 = A  + (size_t)(m0 + srow) * K + scol8;
  const u16* Ag1 = A  + (size_t)(m0 + 64 + srow) * K + scol8;
  const u16* Bg0 = Bt + (size_t)(n0 + srow) * K + scol8;
  const u16* Bg1 = Bt + (size_t)(n0 + 64 + srow) * K + scol8;
  u16* Al0 = As + t * 8;  u16* Al1 = As + 2048 + t * 8;
  u16* Bl0 = Bs + t * 8;  u16* Bl1 = Bs + 2048 + t * 8;

  int lane = t & 63, w = t >> 6;
  int m16 = lane & 15, quad = lane >> 4;
  int wr = (w >> 1) * 64, wc = (w & 1) * 64;

  f32x4 acc[4][4];
#pragma unroll
  for (int mi = 0; mi < 4; ++mi)
#pragma unroll
    for (int ni = 0; ni < 4; ++ni)
#pragma unroll
      for (int r = 0; r < 4; ++r) acc[mi][ni][r] = 0.f;

  for (int k0 = 0; k0 < K; k0 += 32) {
    __syncthreads();
    GLOAD_LDS16(Ag0 + k0, Al0);
    GLOAD_LDS16(Ag1 + k0, Al1);
    GLOAD_LDS16(Bg0 + k0, Bl0);
    GLOAD_LDS16(Bg1 + k0, Bl1);
    __syncthreads();
    s16x8 af[4], bf[4];
#pragma unroll
    for (int mi = 0; mi < 4; ++mi)
      af[mi] = *(const s16x8*)(As + (wr + mi * 16 + m16) * 32 + quad * 8);
#pragma unroll
    for (int ni = 0; ni < 4; ++ni)
      bf[ni] = *(const s16x8*)(Bs + (wc + ni * 16 + m16) * 32 + quad * 8);
#pragma unroll
    for (int mi = 0; mi < 4; ++mi)
#pragma unroll
      for (int ni = 0; ni < 4; ++ni)
        acc[mi][ni] = __builtin_amdgcn_mfma_f32_16x16x32_bf16(af[mi], bf[ni], acc[mi][ni], 0, 0, 0);
  }

  if (EPI == 0) {
#pragma unroll
    for (int mi = 0; mi < 4; ++mi) {
      int gr = m0 + wr + mi * 16 + quad * 4;
#pragma unroll
      for (int ni = 0; ni < 4; ++ni) {
        int gc = n0 + wc + ni * 16 + m16;
#pragma unroll
        for (int r = 0; r < 4; ++r)
          Cf[(size_t)(gr + r) * N + gc] = acc[mi][ni][r];
      }
    }
  } else {
#pragma unroll
    for (int mi = 0; mi < 4; ++mi) {
      int gr = m0 + wr + mi * 16 + quad * 4;
      int b = gr >> 11, tt = gr & 2047;
#pragma unroll
      for (int ni = 0; ni < 4; ++ni) {
        int gc = n0 + wc + ni * 16 + m16;
        int sec = gc >> 10, rem = gc & 1023, h = rem >> 6, d = rem & 63;
        if (sec == 0) {
#pragma unroll
          for (int r = 0; r < 4; ++r)
            Qo[(((size_t)b * NH + h) * SEQ + tt + r) * HD + d] = f32_bf16(acc[mi][ni][r] * QSCALE);
        } else if (sec == 1) {
#pragma unroll
          for (int r = 0; r < 4; ++r)
            Ko[(((size_t)b * NH + h) * SEQ + tt + r) * HD + d] = f32_bf16(acc[mi][ni][r]);
        } else {
          ushort4 o;
          o.x = f32_bf16(acc[mi][ni][0]); o.y = f32_bf16(acc[mi][ni][1]);
          o.z = f32_bf16(acc[mi][ni][2]); o.w = f32_bf16(acc[mi][ni][3]);
          *(ushort4*)&Vo[(((size_t)b * NH + h) * HD + d) * SEQ + tt] = o;
        }
      }
    }
  }
}

// ---------------- flash attention, causal, QBLK=128, swapped-QK^T, NO-MAX softmax ------
// R9: LDS rebuilt in the qkv-proven bank-conflict-free class. The padded [64][72]
// arrays (144B rows) measured 8-10M SQ_LDS_BANK_CONFLICT cycles/dispatch; the qkv
// [.][32]-row + XOR-involution layout measured 0. K/V/P stored as 32-element halves
// with swizzle slot' = slot ^ ((row>>1)&3) on BOTH write and read sides (reg-staged).
// LDS 32 KB (was 27.6); occupancy unchanged (VGPR-limited ~3 blocks/CU).
// Structure otherwise identical to the verified R4 kernel.
__global__ __launch_bounds__(256) void attn_k(
    const u16* __restrict__ Q, const u16* __restrict__ K,
    const u16* __restrict__ Vt_g,   // [B,H,HD,SEQ]
    u16* __restrict__ O)
{
  __shared__ u16 KsL[64][32], KsH[64][32];     // [key][d-half]
  __shared__ u16 VtL[64][32], VtH[64][32];     // [d][key-half]
  __shared__ u16 PsL[4][32][32], PsH[4][32][32]; // per wave: [qrow][key-half]
  int flat = blockIdx.y * 8 + blockIdx.x;    // grid (8, 64) = 512 blocks
  int xcd = flat & 7, pos = flat >> 3;
  int bh = xcd * 8 + (pos >> 3);             // 8 bh per XCD
  int xb = pos & 7;                          // 0..7
  int t = threadIdx.x, w = t >> 6, lane = t & 63;
  int m16 = lane & 15, quad = lane >> 4;
  int b = bh >> 4, h = bh & 15;

  int srow = t >> 2, sc = (t & 3) * 16;      // sc in {0,16,32,48}
  const u16* Kg0 = K    + ((size_t)bh * SEQ + srow) * HD  + sc;   // key=srow, d=sc..
  const u16* Vg0 = Vt_g + ((size_t)bh * HD  + srow) * SEQ + sc;   // d=srow,  key=sc..

  // swizzled staging dests: half = sc>=32; logical chunks lc, lc+1 (lc in {0,2});
  // physical chunk = logical ^ ((srow>>1)&3)
  int rsw = (srow >> 1) & 3;
  int lc = (sc & 31) >> 3;                   // 0 or 2
  int c0 = lc ^ rsw;                         // c1 = c0 ^ 1 (lc even)
  u16* KsD = (sc >= 32 ? &KsH[0][0] : &KsL[0][0]) + srow * 32;
  u16* VtD = (sc >= 32 ? &VtH[0][0] : &VtL[0][0]) + srow * 32;

  // fragment read offset within a [64|32][32] array: row*32 + (quad^((m16>>1)&3))*8
  int kka = (quad ^ ((m16 >> 1) & 3)) * 8;
  // P write: logical chunk cna = (ni&1)*2 + (quad>>1), physical cna ^ ((m16>>1)&3)
  int psw = (m16 >> 1) & 3;

  for (int half = 0; half < 2; ++half) {
    int qt = half ? (15 - xb) : xb;
    int q0 = qt * 128;

    // Q frags: set A rows q0 + w*32 + m16, set B rows +16 (scale pre-folded into Q)
    const u16* QbA = Q + ((size_t)bh * SEQ + q0 + w * 32 + m16) * HD + quad * 8;
    s16x8 qA0 = *(const s16x8*)QbA;
    s16x8 qA1 = *(const s16x8*)(QbA + 32);
    s16x8 qB0 = *(const s16x8*)(QbA + 16 * HD);
    s16x8 qB1 = *(const s16x8*)(QbA + 16 * HD + 32);

    f32x4 accA[4], accB[4];
    float lA = 0.f, lB = 0.f;
#pragma unroll
    for (int ni = 0; ni < 4; ++ni)
#pragma unroll
      for (int r = 0; r < 4; ++r) { accA[ni][r] = 0.f; accB[ni][r] = 0.f; }

    int ktmax = 2 * qt + 1;
    for (int kt = 0; kt <= ktmax; ++kt) {
      uint4 kv0 = *(const uint4*)(Kg0 + (size_t)kt * 64 * HD);
      uint4 kv1 = *(const uint4*)(Kg0 + (size_t)kt * 64 * HD + 8);
      uint4 vv0 = *(const uint4*)(Vg0 + kt * 64);
      uint4 vv1 = *(const uint4*)(Vg0 + kt * 64 + 8);
      __syncthreads();   // previous tile's LDS reads done
      *(uint4*)(KsD + c0 * 8)       = kv0;
      *(uint4*)(KsD + (c0 ^ 1) * 8) = kv1;
      *(uint4*)(VtD + c0 * 8)       = vv0;
      *(uint4*)(VtD + (c0 ^ 1) * 8) = vv1;
      __syncthreads();

      // S^T = K Q^T
      f32x4 sA[4], sB[4];
#pragma unroll
      for (int ni = 0; ni < 4; ++ni)
#pragma unroll
        for (int r = 0; r < 4; ++r) { sA[ni][r] = 0.f; sB[ni][r] = 0.f; }
#pragma unroll
      for (int ni = 0; ni < 4; ++ni) {
        int krow = (ni * 16 + m16) * 32 + kka;
        s16x8 kf0 = *(const s16x8*)(&KsL[0][0] + krow);
        s16x8 kf1 = *(const s16x8*)(&KsH[0][0] + krow);
        sA[ni] = mfma16(kf0, qA0, sA[ni]);
        sA[ni] = mfma16(kf1, qA1, sA[ni]);
        sB[ni] = mfma16(kf0, qB0, sB[ni]);
        sB[ni] = mfma16(kf1, qB1, sB[ni]);
      }
      if (kt >= 2 * qt) {   // diagonal region: causal mask (exp2(-1e30) -> 0)
        int qga = q0 + w * 32 + m16;
#pragma unroll
        for (int ni = 0; ni < 4; ++ni) {
          int kb = kt * 64 + ni * 16 + quad * 4;
#pragma unroll
          for (int r = 0; r < 4; ++r) {
            if (kb + r > qga)      sA[ni][r] = -1e30f;
            if (kb + r > qga + 16) sB[ni][r] = -1e30f;
          }
        }
      }

      // p = exp2(S); per-lane l partial; P write as ushort4 (8B) to swizzled chunk
#pragma unroll
      for (int ni = 0; ni < 4; ++ni) {
        ushort4 oA, oB;
#pragma unroll
        for (int r = 0; r < 4; ++r) {
          float pA = __builtin_amdgcn_exp2f(sA[ni][r]);
          float pB = __builtin_amdgcn_exp2f(sB[ni][r]);
          lA += pA; lB += pB;
          ((u16*)&oA)[r] = f32_bf16_trunc(pA);
          ((u16*)&oB)[r] = f32_bf16_trunc(pB);
        }
        u16* pd = (ni >= 2 ? &PsH[w][0][0] : &PsL[w][0][0]);
        int cs = (((ni & 1) * 2 + (quad >> 1)) ^ psw) * 8 + (quad & 1) * 4;
        *(ushort4*)(pd + m16 * 32 + cs)        = oA;
        *(ushort4*)(pd + (16 + m16) * 32 + cs) = oB;
      }

      // no barrier: Ps is same-wave write->read, ordered by lgkmcnt
#pragma unroll
      for (int ks = 0; ks < 2; ++ks) {
        const u16* ps = ks ? &PsH[w][0][0] : &PsL[w][0][0];
        const u16* vb = ks ? &VtH[0][0] : &VtL[0][0];
        s16x8 pA = *(const s16x8*)(ps + m16 * 32 + kka);
        s16x8 pB = *(const s16x8*)(ps + (16 + m16) * 32 + kka);
#pragma unroll
        for (int ni = 0; ni < 4; ++ni) {
          s16x8 vf = *(const s16x8*)(vb + (ni * 16 + m16) * 32 + kka);
          accA[ni] = mfma16(pA, vf, accA[ni]);
          accB[ni] = mfma16(pB, vf, accB[ni]);
        }
      }
    }

    // l: reduce over the 4 quad lanes (keys split across quads)
    lA += __shfl_xor(lA, 16, 64);
    lA += __shfl_xor(lA, 32, 64);
    lB += __shfl_xor(lB, 16, 64);
    lB += __shfl_xor(lB, 32, 64);

    // epilogue: O rows q = q0 + w*32 + (quad*4+r) [+16 for set B]; l lives at
    // lanes with m16 == qrow -> redistribute with one shfl per r
#pragma unroll
    for (int r = 0; r < 4; ++r) {
      int src = (lane & 48) | (quad * 4 + r);
      float la = __shfl(lA, src, 64);
      float lb = __shfl(lB, src, 64);
      float ia = 1.f / la, ib = 1.f / lb;
      int qa = q0 + w * 32 + quad * 4 + r;
      size_t baseA = ((size_t)(b * SEQ + qa)) * DM + h * HD;
      size_t baseB = baseA + (size_t)16 * DM;
#pragma unroll
      for (int ni = 0; ni < 4; ++ni) {
        O[baseA + ni * 16 + m16] = f32_bf16(accA[ni][r] * ia);
        O[baseB + ni * 16 + m16] = f32_bf16(accB[ni][r] * ib);
      }
    }
  }
}

// ---------------- launch ----------------
extern "C" void kernel_launch(void* const* d_in, const int* in_sizes, int n_in,
                              void* d_out, int out_size, void* d_ws, size_t ws_size,
                              hipStream_t stream) {
  const float* x    = (const float*)d_in[0];   // [4,2048,1024]
  const float* Wqkv = (const float*)d_in[1];   // [1024,3072]
  const float* Wout = (const float*)d_in[2];   // [1024,1024]
  float* out = (float*)d_out;                  // [4,2048,1024] fp32

  u16* ws = (u16*)d_ws;
  size_t off = 0;
  u16* x_bf   = ws + off; off += (size_t)ROWS * DM;
  u16* wqkv_t = ws + off; off += (size_t)(3 * DM) * DM;
  u16* wout_t = ws + off; off += (size_t)DM * DM;
  u16* Qb     = ws + off; off += (size_t)BATCH * NH * SEQ * HD;
  u16* Kb     = ws + off; off += (size_t)BATCH * NH * SEQ * HD;
  u16* Vb     = ws + off; off += (size_t)BATCH * NH * SEQ * HD;  // [B,H,HD,T]
  u16* AO     = ws + off; off += (size_t)ROWS * DM;

  cast_bf16_k<<<(ROWS * DM / 4 + 255) / 256, 256, 0, stream>>>(x, x_bf, ROWS * DM / 4);
  cast_transpose_k<<<dim3(3 * DM / 32, DM / 32), 256, 0, stream>>>(Wqkv, wqkv_t, DM, 3 * DM);
  cast_transpose_k<<<dim3(DM / 32, DM / 32), 256, 0, stream>>>(Wout, wout_t, DM, DM);
  qkv_gemm<<<dim3(8, 64), 512, 0, stream>>>(x_bf, wqkv_t, Qb, Kb, Vb);
  attn_k<<<dim3(8, BATCH * NH), 256, 0, stream>>>(Qb, Kb, Vb, AO);
  gemm_bt<0><<<dim3(DM / 128, ROWS / 128), 256, 0, stream>>>(
      AO, wout_t, out, nullptr, nullptr, nullptr, ROWS, DM, DM);
}